// Round 10
// baseline (327.880 us; speedup 1.0000x reference)
//
#include <hip/hip_runtime.h>

#define NEG_SLOPE 0.1f

typedef __bf16 bf16x8 __attribute__((ext_vector_type(8)));
typedef float f32x4 __attribute__((ext_vector_type(4)));
typedef unsigned int uint32x4 __attribute__((ext_vector_type(4)));
typedef unsigned short ushort;

__device__ inline ushort f2bf(float f) {
    unsigned int u = __float_as_uint(f);
    u += 0x7fffu + ((u >> 16) & 1u);
    return (ushort)(u >> 16);
}
__device__ inline float bf2f(ushort h) { return __uint_as_float(((unsigned int)h) << 16); }

__device__ inline void pack8(const float* v, uint32x4& hv, uint32x4& lv) {
    ushort hi[8], lo[8];
#pragma unroll
    for (int j = 0; j < 8; j++) {
        float f = v[j];
        ushort h = f2bf(f);
        hi[j] = h;
        lo[j] = f2bf(f - bf2f(h));
    }
    hv.x = hi[0] | ((unsigned)hi[1] << 16); hv.y = hi[2] | ((unsigned)hi[3] << 16);
    hv.z = hi[4] | ((unsigned)hi[5] << 16); hv.w = hi[6] | ((unsigned)hi[7] << 16);
    lv.x = lo[0] | ((unsigned)lo[1] << 16); lv.y = lo[2] | ((unsigned)lo[3] << 16);
    lv.z = lo[4] | ((unsigned)lo[5] << 16); lv.w = lo[6] | ((unsigned)lo[7] << 16);
}

// accumulate one 16B chunk (8 bf16) into 8 f32 accumulators
__device__ inline void acc8(const uint32x4 u, float* a) {
    a[0] += __uint_as_float(u.x << 16); a[1] += __uint_as_float(u.x & 0xffff0000u);
    a[2] += __uint_as_float(u.y << 16); a[3] += __uint_as_float(u.y & 0xffff0000u);
    a[4] += __uint_as_float(u.z << 16); a[5] += __uint_as_float(u.z & 0xffff0000u);
    a[6] += __uint_as_float(u.w << 16); a[7] += __uint_as_float(u.w & 0xffff0000u);
}

// ---------------- CSR build ----------------
// Pass 1: degree count (padded, 1 counter per 64B line) + per-edge rank (coalesced).
__global__ void k_count(const int* __restrict__ ei, int E, int* __restrict__ degp,
                        int* __restrict__ rank) {
    int e = blockIdx.x * 256 + threadIdx.x;
    if (e < E) rank[e] = atomicAdd(&degp[(size_t)ei[E + e] * 16], 1);
}

__global__ void k_starts(const int* __restrict__ degp, int N, int* __restrict__ start,
                         int* __restrict__ deg, int* __restrict__ counter) {
    int n = blockIdx.x * 256 + threadIdx.x;
    int lane = threadIdx.x & 63;
    int d = (n < N) ? degp[(size_t)n * 16] : 0;
    int inc = d;
#pragma unroll
    for (int o = 1; o < 64; o <<= 1) {
        int v = __shfl_up(inc, o);
        if (lane >= o) inc += v;
    }
    int total = __shfl(inc, 63);
    int base = 0;
    if (lane == 0) base = atomicAdd(counter, total);
    base = __shfl(base, 0);
    int st = base + inc - d;
    if (n < N) { start[n] = st; deg[n] = d; }
}

// Pass 3: atomic-free scatter.
__global__ void k_fill(const int* __restrict__ ei, int E, const int* __restrict__ start,
                       const int* __restrict__ rank, int* __restrict__ adj) {
    int e = blockIdx.x * 256 + threadIdx.x;
    if (e < E) {
        int s = ei[e];
        int dv = ei[E + e];
        adj[start[dv] + rank[e]] = s;
    }
}

// ---------------- weight pre-pack: W[K][Nn] f32 -> packed hi/lo bf16 ----------------
// packed layout: [Nn/16 cb][16 kg][16 col][8 k]

__global__ __launch_bounds__(256) void k_wpack(const float* __restrict__ wl,
                                               const float* __restrict__ wr,
                                               const float* __restrict__ wlin,
                                               const float* __restrict__ wout,
                                               ushort* __restrict__ wph,
                                               ushort* __restrict__ wpl) {
    int m = blockIdx.y;
    int c = blockIdx.x * 256 + threadIdx.x;
    const float* src;
    int Nn = 128;
    size_t dstoff;
    if (m < 3)      { src = wl   + (size_t)m * 16384;       dstoff = (size_t)m * 16384; }
    else if (m < 6) { src = wr   + (size_t)(m - 3) * 16384; dstoff = (size_t)m * 16384; }
    else if (m < 8) { src = wlin + (size_t)(m - 6) * 16384; dstoff = (size_t)m * 16384; }
    else            { src = wout; Nn = 64;                  dstoff = (size_t)8 * 16384; }
    if (c >= Nn * 16) return;
    int cb = c >> 8, gg = (c >> 4) & 15, col = c & 15;
    float v[8];
#pragma unroll
    for (int j = 0; j < 8; j++)
        v[j] = src[(size_t)(gg * 8 + j) * Nn + cb * 16 + col];
    uint32x4 hv, lv;
    pack8(v, hv, lv);
    *(uint32x4*)(wph + dstoff + (size_t)c * 8) = hv;
    *(uint32x4*)(wpl + dstoff + (size_t)c * 8) = lv;
}

// ---------------- x f32 -> row-major hi/lo bf16 ----------------

__global__ __launch_bounds__(256) void k_splitx(const float* __restrict__ x,
                                                ushort* __restrict__ oh,
                                                ushort* __restrict__ ol, int N) {
    int t = blockIdx.x * 256 + threadIdx.x;
    int row = t >> 4, g = t & 15;
    if (row >= N) return;
    const float* src = x + (size_t)row * 128 + g * 8;
    float v[8];
#pragma unroll
    for (int j = 0; j < 8; j++) v[j] = src[j];
    uint32x4 hv, lv;
    pack8(v, hv, lv);
    size_t off = (size_t)row * 128 + g * 8;
    *(uint32x4*)(oh + off) = hv;
    *(uint32x4*)(ol + off) = lv;
}

// ---------------- fused layer kernel: agg + conv dual-GEMM + lin GEMM ----------------
// Block = 32 rows x 128 cols, 4 waves (each a 32-col slice), grid = ceil(N/32).
// Phase A: quarter-wave-per-node mean gather; each node's edge list is split into
//          two half-streams with separate accumulators -> 8 gathers in flight/lane.
// Stage 1: conv = [act](agg@W1 + h@W2 + b1); A1 from LDS, A2 (self) from global.
// Stage 2: out = [act](conv@W3 + b2) -> global rm hi/lo, or f32 d_out (FINAL).

template <bool ACT1, int NM2, bool ACT2, bool FINAL>
__global__ __launch_bounds__(256) void k_fused(
    const ushort* __restrict__ hh,   const ushort* __restrict__ hl,
    const int* __restrict__ adj, const int* __restrict__ start,
    const int* __restrict__ deg,
    const ushort* __restrict__ w1h,  const ushort* __restrict__ w1l,
    const ushort* __restrict__ w2h,  const ushort* __restrict__ w2l,
    const float* __restrict__ b1,
    const ushort* __restrict__ w3h,  const ushort* __restrict__ w3l,
    const float* __restrict__ b2,
    ushort* __restrict__ oh, ushort* __restrict__ ol,
    float* __restrict__ of, int N) {
    constexpr int NCF2 = NM2 / 64;  // stage-2 col fragments per wave
    __shared__ ushort th[32][136];  // agg tile, then conv result (hi)
    __shared__ ushort tl[32][136];  // (lo)

    const int tid = threadIdx.x;
    const int w = tid >> 6, lane = tid & 63;
    const int g = lane >> 4, r16 = lane & 15;
    const int m0 = blockIdx.x * 32;

    // ---------------- phase A: mean aggregation into LDS ----------------
    {
        const int qw = tid >> 4;   // quarter-wave id 0..15
        const int q = tid & 15;    // lane-in-quarter: owns cols q*8..q*8+7
#pragma unroll
        for (int rep = 0; rep < 2; rep++) {
            int nr = qw + rep * 16;          // block-local row 0..31
            int node = m0 + nr;
            if (node > N - 1) node = N - 1;
            const int st = start[node], cnt = deg[node];
            const int h = cnt >> 1;
            const int stB = st + h;          // stream B: [st+h, st+cnt)
            float a[8] = {0, 0, 0, 0, 0, 0, 0, 0};
            float b[8] = {0, 0, 0, 0, 0, 0, 0, 0};
            int i = 0;
            for (; i + 4 <= h; i += 4) {     // 8 gathers in flight
                int s0 = adj[st + i], s1 = adj[st + i + 1];
                int s2 = adj[st + i + 2], s3 = adj[st + i + 3];
                int t0 = adj[stB + i], t1 = adj[stB + i + 1];
                int t2 = adj[stB + i + 2], t3 = adj[stB + i + 3];
                uint32x4 u0 = *(const uint32x4*)(hh + (size_t)s0 * 128 + q * 8);
                uint32x4 u1 = *(const uint32x4*)(hh + (size_t)s1 * 128 + q * 8);
                uint32x4 u2 = *(const uint32x4*)(hh + (size_t)s2 * 128 + q * 8);
                uint32x4 u3 = *(const uint32x4*)(hh + (size_t)s3 * 128 + q * 8);
                uint32x4 v0 = *(const uint32x4*)(hh + (size_t)t0 * 128 + q * 8);
                uint32x4 v1 = *(const uint32x4*)(hh + (size_t)t1 * 128 + q * 8);
                uint32x4 v2 = *(const uint32x4*)(hh + (size_t)t2 * 128 + q * 8);
                uint32x4 v3 = *(const uint32x4*)(hh + (size_t)t3 * 128 + q * 8);
                acc8(u0, a); acc8(u1, a); acc8(u2, a); acc8(u3, a);
                acc8(v0, b); acc8(v1, b); acc8(v2, b); acc8(v3, b);
            }
            const int im = i;
            for (; i < h; i++) {             // stream-A tail (<4)
                int s0 = adj[st + i];
                uint32x4 u = *(const uint32x4*)(hh + (size_t)s0 * 128 + q * 8);
                acc8(u, a);
            }
            for (int j = stB + im; j < st + cnt; j++) {  // stream-B tail (<5)
                int t0 = adj[j];
                uint32x4 u = *(const uint32x4*)(hh + (size_t)t0 * 128 + q * 8);
                acc8(u, b);
            }
            float inv = 1.0f / fmaxf((float)cnt, 1.0f);
            float v[8];
#pragma unroll
            for (int c = 0; c < 8; c++) v[c] = (a[c] + b[c]) * inv;
            uint32x4 hv, lv;
            pack8(v, hv, lv);
            *(uint32x4*)&th[nr][q * 8] = hv;
            *(uint32x4*)&tl[nr][q * 8] = lv;
        }
    }
    __syncthreads();

    // ---------------- stage 1: conv dual-GEMM ----------------
    size_t ro[2];
#pragma unroll
    for (int rf = 0; rf < 2; rf++) {
        int row = m0 + rf * 16 + r16;
        if (row > N - 1) row = N - 1;
        ro[rf] = (size_t)row * 128 + g * 8;
    }

    f32x4 acc[2][2];
#pragma unroll
    for (int rf = 0; rf < 2; rf++)
#pragma unroll
        for (int cf = 0; cf < 2; cf++) acc[rf][cf] = (f32x4){0.f, 0.f, 0.f, 0.f};

#pragma unroll
    for (int s = 0; s < 4; s++) {
        bf16x8 a1h_[2], a1l_[2], a2h_[2], a2l_[2];
#pragma unroll
        for (int rf = 0; rf < 2; rf++) {
            a1h_[rf] = *(const bf16x8*)&th[rf * 16 + r16][s * 32 + g * 8];
            a1l_[rf] = *(const bf16x8*)&tl[rf * 16 + r16][s * 32 + g * 8];
            a2h_[rf] = *(const bf16x8*)(hh + ro[rf] + s * 32);
            a2l_[rf] = *(const bf16x8*)(hl + ro[rf] + s * 32);
        }
        bf16x8 b1h_[2], b1l_[2], b2h_[2], b2l_[2];
#pragma unroll
        for (int cf = 0; cf < 2; cf++) {
            size_t o = (size_t)(w * 2 + cf) * 2048 + s * 512 + g * 128 + r16 * 8;
            b1h_[cf] = *(const bf16x8*)(w1h + o);
            b1l_[cf] = *(const bf16x8*)(w1l + o);
            b2h_[cf] = *(const bf16x8*)(w2h + o);
            b2l_[cf] = *(const bf16x8*)(w2l + o);
        }
#pragma unroll
        for (int rf = 0; rf < 2; rf++)
#pragma unroll
            for (int cf = 0; cf < 2; cf++) {
                acc[rf][cf] = __builtin_amdgcn_mfma_f32_16x16x32_bf16(a1h_[rf], b1h_[cf], acc[rf][cf], 0, 0, 0);
                acc[rf][cf] = __builtin_amdgcn_mfma_f32_16x16x32_bf16(a1h_[rf], b1l_[cf], acc[rf][cf], 0, 0, 0);
                acc[rf][cf] = __builtin_amdgcn_mfma_f32_16x16x32_bf16(a1l_[rf], b1h_[cf], acc[rf][cf], 0, 0, 0);
                acc[rf][cf] = __builtin_amdgcn_mfma_f32_16x16x32_bf16(a2h_[rf], b2h_[cf], acc[rf][cf], 0, 0, 0);
                acc[rf][cf] = __builtin_amdgcn_mfma_f32_16x16x32_bf16(a2h_[rf], b2l_[cf], acc[rf][cf], 0, 0, 0);
                acc[rf][cf] = __builtin_amdgcn_mfma_f32_16x16x32_bf16(a2l_[rf], b2h_[cf], acc[rf][cf], 0, 0, 0);
            }
    }
    __syncthreads();  // all stage-1 LDS reads done before overwrite

    // ---------------- epilogue 1: bias/act -> conv hi/lo into th/tl ----------------
    {
        float bv1[2];
#pragma unroll
        for (int cf = 0; cf < 2; cf++) bv1[cf] = b1[(w * 2 + cf) * 16 + r16];
#pragma unroll
        for (int rf = 0; rf < 2; rf++)
#pragma unroll
            for (int cf = 0; cf < 2; cf++)
#pragma unroll
                for (int i = 0; i < 4; i++) {
                    float v = acc[rf][cf][i] + bv1[cf];
                    if (ACT1) v = v > 0.f ? v : NEG_SLOPE * v;
                    ushort hi = f2bf(v);
                    ushort lo = f2bf(v - bf2f(hi));
                    th[rf * 16 + g * 4 + i][w * 32 + cf * 16 + r16] = hi;
                    tl[rf * 16 + g * 4 + i][w * 32 + cf * 16 + r16] = lo;
                }
    }
    __syncthreads();

    // ---------------- stage 2: out GEMM (A from LDS th/tl) ----------------
    f32x4 acc2[2][NCF2];
#pragma unroll
    for (int rf = 0; rf < 2; rf++)
#pragma unroll
        for (int cf = 0; cf < NCF2; cf++) acc2[rf][cf] = (f32x4){0.f, 0.f, 0.f, 0.f};

#pragma unroll
    for (int s = 0; s < 4; s++) {
        bf16x8 ah_[2], al_[2];
#pragma unroll
        for (int rf = 0; rf < 2; rf++) {
            ah_[rf] = *(const bf16x8*)&th[rf * 16 + r16][s * 32 + g * 8];
            al_[rf] = *(const bf16x8*)&tl[rf * 16 + r16][s * 32 + g * 8];
        }
        bf16x8 wh_[NCF2], wlo_[NCF2];
#pragma unroll
        for (int cf = 0; cf < NCF2; cf++) {
            size_t o = (size_t)(w * NCF2 + cf) * 2048 + s * 512 + g * 128 + r16 * 8;
            wh_[cf] = *(const bf16x8*)(w3h + o);
            wlo_[cf] = *(const bf16x8*)(w3l + o);
        }
#pragma unroll
        for (int rf = 0; rf < 2; rf++)
#pragma unroll
            for (int cf = 0; cf < NCF2; cf++) {
                acc2[rf][cf] = __builtin_amdgcn_mfma_f32_16x16x32_bf16(ah_[rf], wh_[cf], acc2[rf][cf], 0, 0, 0);
                acc2[rf][cf] = __builtin_amdgcn_mfma_f32_16x16x32_bf16(ah_[rf], wlo_[cf], acc2[rf][cf], 0, 0, 0);
                acc2[rf][cf] = __builtin_amdgcn_mfma_f32_16x16x32_bf16(al_[rf], wh_[cf], acc2[rf][cf], 0, 0, 0);
            }
    }

    // ---------------- epilogue 2 ----------------
    if constexpr (FINAL) {
        float bv2 = b2[w * 16 + r16];
#pragma unroll
        for (int rf = 0; rf < 2; rf++)
#pragma unroll
            for (int i = 0; i < 4; i++) {
                int row = m0 + rf * 16 + g * 4 + i;
                if (row < N) of[(size_t)row * 64 + w * 16 + r16] = acc2[rf][0][i] + bv2;
            }
    } else {
        __syncthreads();  // all stage-2 reads of th/tl done before reuse
        float bv2[2];
#pragma unroll
        for (int cf = 0; cf < 2; cf++) bv2[cf] = b2[(w * 2 + cf) * 16 + r16];
#pragma unroll
        for (int rf = 0; rf < 2; rf++)
#pragma unroll
            for (int cf = 0; cf < 2; cf++)
#pragma unroll
                for (int i = 0; i < 4; i++) {
                    float v = acc2[rf][cf][i] + bv2[cf];
                    if (ACT2) v = v > 0.f ? v : NEG_SLOPE * v;
                    ushort hi = f2bf(v);
                    ushort lo = f2bf(v - bf2f(hi));
                    th[rf * 16 + g * 4 + i][w * 32 + cf * 16 + r16] = hi;
                    tl[rf * 16 + g * 4 + i][w * 32 + cf * 16 + r16] = lo;
                }
        __syncthreads();
#pragma unroll
        for (int rep = 0; rep < 2; rep++) {
            int id = rep * 256 + tid;       // 0..511
            int row = id >> 4, kg = id & 15;
            int grow = m0 + row;
            if (grow < N) {
                uint32x4 hv = *(const uint32x4*)&th[row][kg * 8];
                uint32x4 lv = *(const uint32x4*)&tl[row][kg * 8];
                *(uint32x4*)(oh + (size_t)grow * 128 + kg * 8) = hv;
                *(uint32x4*)(ol + (size_t)grow * 128 + kg * 8) = lv;
            }
        }
    }
}

// ---------------- launch ----------------

extern "C" void kernel_launch(void* const* d_in, const int* in_sizes, int n_in,
                              void* d_out, int out_size, void* d_ws, size_t ws_size,
                              hipStream_t stream) {
    const float* x    = (const float*)d_in[0];
    const int*   ei   = (const int*)d_in[1];
    const float* wl   = (const float*)d_in[2];
    const float* wr   = (const float*)d_in[3];
    const float* bc   = (const float*)d_in[4];
    const float* wlin = (const float*)d_in[5];
    const float* blin = (const float*)d_in[6];
    const float* wout = (const float*)d_in[7];
    const float* bout = (const float*)d_in[8];
    float* out = (float*)d_out;

    const int N = in_sizes[0] / 128;
    const int E = in_sizes[1] / 2;

    char* p = (char*)d_ws;
    auto alloc = [&](size_t bytes) {
        char* r = p;
        p += (bytes + 255) & ~(size_t)255;
        return r;
    };
    int* counter = (int*)alloc(4);
    int* degp    = (int*)alloc((size_t)N * 16 * 4);  // padded: 1 counter / 64B line
    int* deg     = (int*)alloc((size_t)N * 4);
    int* start   = (int*)alloc((size_t)N * 4);
    int* rank    = (int*)alloc((size_t)E * 4);
    int* adj     = (int*)alloc((size_t)E * 4);
    ushort* wph  = (ushort*)alloc((size_t)139264 * 2);
    ushort* wpl  = (ushort*)alloc((size_t)139264 * 2);
    ushort* xh   = (ushort*)alloc((size_t)N * 128 * 2);  // reused as layer-1 output
    ushort* xl   = (ushort*)alloc((size_t)N * 128 * 2);
    ushort* hAh  = (ushort*)alloc((size_t)N * 128 * 2);  // layer-0 output
    ushort* hAl  = (ushort*)alloc((size_t)N * 128 * 2);

    // zero counter + degp (contiguous at the front of ws)
    hipMemsetAsync(d_ws, 0, (size_t)((char*)(degp + (size_t)N * 16) - (char*)d_ws), stream);

    const int gE = (E + 255) / 256;
    const int gN = (N + 255) / 256;
    const int gQ = (N * 16 + 255) / 256;
    const int gF = (N + 31) / 32;   // fused layer blocks (32 rows)

    k_count <<<gE, 256, 0, stream>>>(ei, E, degp, rank);
    k_starts<<<gN, 256, 0, stream>>>(degp, N, start, deg, counter);
    k_fill  <<<gE, 256, 0, stream>>>(ei, E, start, rank, adj);
    k_wpack <<<dim3(8, 9), 256, 0, stream>>>(wl, wr, wlin, wout, wph, wpl);
    k_splitx<<<gQ, 256, 0, stream>>>(x, xh, xl, N);

    const ushort *wl0h = wph,           *wl0l = wpl;
    const ushort *wl1h = wph + 16384,   *wl1l = wpl + 16384;
    const ushort *wl2h = wph + 32768,   *wl2l = wpl + 32768;
    const ushort *wr0h = wph + 3*16384, *wr0l = wpl + 3*16384;
    const ushort *wr1h = wph + 4*16384, *wr1l = wpl + 4*16384;
    const ushort *wr2h = wph + 5*16384, *wr2l = wpl + 5*16384;
    const ushort *wn0h = wph + 6*16384, *wn0l = wpl + 6*16384;
    const ushort *wn1h = wph + 7*16384, *wn1l = wpl + 7*16384;
    const ushort *woh  = wph + 8*16384, *wol  = wpl + 8*16384;

    // layer 0: h = x
    k_fused<true, 128, true, false><<<gF, 256, 0, stream>>>(
        xh, xl, adj, start, deg, wl0h, wl0l, wr0h, wr0l, bc,
        wn0h, wn0l, blin, hAh, hAl, nullptr, N);
    // layer 1: h = hA -> writes xh/xl (x dead)
    k_fused<true, 128, true, false><<<gF, 256, 0, stream>>>(
        hAh, hAl, adj, start, deg, wl1h, wl1l, wr1h, wr1l, bc + 128,
        wn1h, wn1l, blin + 128, xh, xl, nullptr, N);
    // layer 2: conv (no act) + wout projection -> d_out
    k_fused<false, 64, false, true><<<gF, 256, 0, stream>>>(
        xh, xl, adj, start, deg, wl2h, wl2l, wr2h, wr2l, bc + 256,
        woh, wol, bout, nullptr, nullptr, out, N);
}